// Round 9
// baseline (64.180 us; speedup 1.0000x reference)
//
#include <hip/hip_runtime.h>

#define B_N   2048
#define LQ    10
#define LH    150

// LDS arena (floats):
//   XS [0,720)     : padded X, ch*360 + (row+1)*20 + (col+1)   (stride 20)
//   RP [720,1080)  : padded r, stride 20
//   VP [1080,2808) : double-buffered padded v, STRIDE 48 (48%32=16 -> a
//                    wave's 4 rows hit banks {0,16,0,16}+c = exact 2-way, free)
//   EF [2808,2836) : [0..17] eff_w, [18] eff_b, [19..27] fw
//   SCR[2836,3092) : reduction scratch (1 slot/thread)
#define XS    0
#define RP    720
#define VP    1080
#define VS    48          // v row stride
#define VB    864         // v buffer size (18*48)
#define EF    2808
#define SCR   2836
#define SMEMN 3092

// 256 threads (4 waves) per batch element, 1 pixel/lane: tid = i*16 + c.
// 2048 blocks * 4 waves = 8192 waves = 8 waves/SIMD (hardware max TLP) --
// R8 showed we're stall-bound (VALUBusy 54%, pipes only ~50% subscribed),
// so this doubles latency hiding while halving per-wave step work.
// VI weights via wave-uniform w[] loads -> SGPRs (R5/R8 evidence: SGPR=112,
// VGPR=28). No runtime indexing into register arrays (round-4 lesson).
__global__ __launch_bounds__(256, 8) void vin_kernel(
    const float* __restrict__ X,   const float* __restrict__ S1,
    const float* __restrict__ S2,  const float* __restrict__ h_w,
    const float* __restrict__ h_b, const float* __restrict__ r_w,
    const float* __restrict__ qw,  const float* __restrict__ w,
    const float* __restrict__ fcw, float* __restrict__ out)
{
    __shared__ float smem[SMEMN];

    const int b   = blockIdx.x;
    const int tid = threadIdx.x;
    const int i   = tid >> 4;     // pixel row 0..15
    const int c   = tid & 15;     // pixel col 0..15

    // ---- issue X loads first (HBM latency overlaps weight reduction) ----
    const float* Xb = X + (size_t)b * 512;
    float x0 = Xb[tid], x1 = Xb[tid + 256];

    // ---- zero arena (conv borders must be 0) ----
    #pragma unroll
    for (int k = 0; k < 13; ++k) {
        int idx = tid + (k << 8);
        if (idx < SMEMN) smem[idx] = 0.f;
    }

    // ---- collapsed-weight partials: 14 lanes/tap, 11 h's per lane ----
    float part = 0.f;
    if (tid < 252) {
        const int t  = tid / 14;
        const int j  = tid - t * 14;
        const int h0 = j * 11;
        const int h1 = (h0 + 11 < LH) ? h0 + 11 : LH;
        for (int h = h0; h < h1; ++h) part += r_w[h] * h_w[h * 18 + t];
    } else {
        const int h0 = (tid - 252) * 38;
        const int h1 = (h0 + 38 < LH) ? h0 + 38 : LH;
        for (int h = h0; h < h1; ++h) part += r_w[h] * h_b[h];
    }
    __syncthreads();                       // zero-fill visible

    smem[SCR + tid] = part;
    // stage X into padded LDS (stride 20)
    smem[XS +       (i + 1) * 20 + c + 1] = x0;
    smem[XS + 360 + (i + 1) * 20 + c + 1] = x1;
    __syncthreads();

    if (tid < 18) {
        float s = 0.f;
        #pragma unroll
        for (int j = 0; j < 14; ++j) s += smem[SCR + tid * 14 + j];
        smem[EF + tid] = s;
    } else if (tid == 18) {
        smem[EF + 18] = smem[SCR + 252] + smem[SCR + 253]
                      + smem[SCR + 254] + smem[SCR + 255];
    } else if (tid >= 19 && tid < 28) {
        const int t = tid - 19;
        float acc = 0.f;
        #pragma unroll
        for (int a = 0; a < LQ; ++a) acc += fcw[a] * w[a * 9 + t];
        smem[EF + tid] = acc;              // fw
    }
    __syncthreads();

    // ---- r = conv3x3(X, eff_w) + eff_b (1 px/lane) ----
    float ew[19];
    #pragma unroll
    for (int t = 0; t < 19; ++t) ew[t] = smem[EF + t];

    {
        float acc = ew[18];
        #pragma unroll
        for (int ch = 0; ch < 2; ++ch)
            #pragma unroll
            for (int ky = 0; ky < 3; ++ky)
                #pragma unroll
                for (int kx = 0; kx < 3; ++kx)
                    acc += smem[XS + ch * 360 + (i + ky) * 20 + c + kx]
                         * ew[ch * 9 + ky * 3 + kx];
        smem[RP + (i + 1) * 20 + c + 1] = acc;
    }
    __syncthreads();

    // ---- qr[a] = conv3x3(r, q_w)[a] (iteration-invariant half) ----
    float rt[3][3];
    #pragma unroll
    for (int ky = 0; ky < 3; ++ky)
        #pragma unroll
        for (int kx = 0; kx < 3; ++kx)
            rt[ky][kx] = smem[RP + (i + ky) * 20 + c + kx];

    float qr[LQ];
    #pragma unroll
    for (int a = 0; a < LQ; ++a) {
        float acc = 0.f;
        #pragma unroll
        for (int ky = 0; ky < 3; ++ky)
            #pragma unroll
            for (int kx = 0; kx < 3; ++kx)
                acc += rt[ky][kx] * qw[a * 9 + ky * 3 + kx];
        qr[a] = acc;
    }

    // ---- VI weights + fc via wave-uniform loads -> SGPRs ----
    float wr[LQ * 9];
    #pragma unroll
    for (int t = 0; t < LQ * 9; ++t) wr[t] = w[t];
    float fc[LQ];
    #pragma unroll
    for (int a = 0; a < LQ; ++a) fc[a] = fcw[a];

    // ---- v0 = max_a qr ----
    {
        float m = qr[0];
        #pragma unroll
        for (int a = 1; a < LQ; ++a) m = fmaxf(m, qr[a]);
        smem[VP + (i + 1) * VS + c + 1] = m;
    }
    __syncthreads();

    // ---- 19 VI sweeps: 9 const-offset taps (merge to ds_read2), 1 write ----
#define VSTEP(SRC, DST)                                                        \
    {                                                                          \
        float vt[3][3];                                                        \
        _Pragma("unroll")                                                      \
        for (int ky = 0; ky < 3; ++ky)                                         \
            _Pragma("unroll")                                                  \
            for (int kx = 0; kx < 3; ++kx)                                     \
                vt[ky][kx] = smem[VP + (SRC) + (i + ky) * VS + c + kx];        \
        float m;                                                               \
        _Pragma("unroll")                                                      \
        for (int a = 0; a < LQ; ++a) {                                         \
            float acc = qr[a];                                                 \
            _Pragma("unroll")                                                  \
            for (int ky = 0; ky < 3; ++ky) {                                   \
                acc += vt[ky][0] * wr[a * 9 + ky * 3 + 0];                     \
                acc += vt[ky][1] * wr[a * 9 + ky * 3 + 1];                     \
                acc += vt[ky][2] * wr[a * 9 + ky * 3 + 2];                     \
            }                                                                  \
            m = (a == 0) ? acc : fmaxf(m, acc);                                \
        }                                                                      \
        smem[VP + (DST) + (i + 1) * VS + c + 1] = m;                           \
        __syncthreads();                                                       \
    }

    #pragma unroll 1
    for (int it = 0; it < 9; ++it) {
        VSTEP(0, VB)
        VSTEP(VB, 0)
    }
    VSTEP(0, VB)   // step 19; final v in VP+VB

    // ---- final conv + gather + fc at (s1, s2) only ----
    const float s1f = S1[b], s2f = S2[b];
    int s1 = (int)floorf((s1f + 50.0f) / 6.25f);
    int s2 = (int)floorf((s2f + 50.0f) / 6.25f);
    s1 = min(max(s1, 0), 15);
    s2 = min(max(s2, 0), 15);

    if (i == s1 && c == s2) {
        float logit = 0.f;
        #pragma unroll
        for (int a = 0; a < LQ; ++a) logit += fc[a] * qr[a];
        #pragma unroll
        for (int ky = 0; ky < 3; ++ky)
            #pragma unroll
            for (int kx = 0; kx < 3; ++kx)
                logit += smem[VP + VB + (s1 + ky) * VS + s2 + kx]
                       * smem[EF + 19 + ky * 3 + kx];
        out[b]       = logit;   // logits
        out[B_N + b] = 1.0f;    // softmax over length-1 axis == 1
    }
#undef VSTEP
}

extern "C" void kernel_launch(void* const* d_in, const int* in_sizes, int n_in,
                              void* d_out, int out_size, void* d_ws, size_t ws_size,
                              hipStream_t stream) {
    const float* X    = (const float*)d_in[0];
    const float* S1   = (const float*)d_in[1];
    const float* S2   = (const float*)d_in[2];
    const float* h_w  = (const float*)d_in[3];
    const float* h_b  = (const float*)d_in[4];
    const float* r_w  = (const float*)d_in[5];
    const float* q_w  = (const float*)d_in[6];
    const float* w    = (const float*)d_in[7];
    const float* fc_w = (const float*)d_in[8];
    float*       out  = (float*)d_out;

    vin_kernel<<<B_N, 256, 0, stream>>>(X, S1, S2, h_w, h_b, r_w, q_w, w, fc_w, out);
}

// Round 10
// 45.722 us; speedup vs baseline: 1.4037x; 1.4037x over previous
//
#include <hip/hip_runtime.h>

#define B_N   2048
#define LQ    10
#define LH    150

// ---------------- pre-kernel: collapse the linear layers once ----------------
// ws layout (floats): [0..17] eff_w (ch*9+ky*3+kx), [18] eff_b, [19..27] fw
__global__ void vin_precompute(const float* __restrict__ h_w,
                               const float* __restrict__ h_b,
                               const float* __restrict__ r_w,
                               const float* __restrict__ w,
                               const float* __restrict__ fc_w,
                               float* __restrict__ ws) {
    const int t = threadIdx.x;
    if (t < 18) {
        float acc = 0.f;
        #pragma unroll 3
        for (int h = 0; h < LH; ++h) acc += r_w[h] * h_w[h * 18 + t];
        ws[t] = acc;
    } else if (t == 18) {
        float acc = 0.f;
        #pragma unroll 3
        for (int h = 0; h < LH; ++h) acc += r_w[h] * h_b[h];
        ws[18] = acc;
    } else if (t < 28) {
        const int tt = t - 19;
        float acc = 0.f;
        #pragma unroll
        for (int a = 0; a < LQ; ++a) acc += fc_w[a] * w[a * 9 + tt];
        ws[19 + tt] = acc;
    }
}

// ---------------- main kernel ----------------
// LDS arena (floats), ROW STRIDE 40: for any fixed tap (dy,dx) a wave's 64
// lanes hit banks dy*8+{0,16}+c = exact 2-way aliasing = free (m136).
//   XS [0,1440)    : padded X, ch*720 + (row+1)*40 + (col+1)
//   RP [1440,2160) : padded r
//   VP [2160,3600) : double-buffered padded v (VP+0 / VP+720)
#define ST    40
#define XS    0
#define RP    1440
#define VP    2160
#define VB    720
#define SMEMN 3600

// 128 threads (2 waves)/batch element, 2 px/lane: tid = rg*16+c, rg=0..7 owns
// rows 2rg,2rg+1, col c. 2048 blocks x 2 waves = 4 waves/SIMD (R8's sweet
// spot). Weight reduction hoisted to vin_precompute (R8 spent ~2850 strided
// loads + 2 barriers per block on it). VI weights via wave-uniform w[] loads
// -> SGPRs (R8 evidence: SGPR=112, VGPR=28). launch_bounds kept at (128,4):
// R7/R9 showed tighter caps inflate dynamic VALU work 2x (compiler
// rematerialization); looser caps risk losing 4 waves/SIMD.
// No runtime indexing into register arrays (round-4 lesson).
__global__ __launch_bounds__(128, 4) void vin_kernel(
    const float* __restrict__ X,   const float* __restrict__ S1,
    const float* __restrict__ S2,  const float* __restrict__ qw,
    const float* __restrict__ w,   const float* __restrict__ fcw,
    const float* __restrict__ ws,  float* __restrict__ out)
{
    __shared__ float smem[SMEMN];

    const int b   = blockIdx.x;
    const int tid = threadIdx.x;
    const int rg  = tid >> 4;     // 0..7
    const int c   = tid & 15;

    // ---- issue X loads first ----
    const float* Xb = X + (size_t)b * 512;
    float xreg[4];
    #pragma unroll
    for (int k = 0; k < 4; ++k) xreg[k] = Xb[tid + (k << 7)];

    // ---- collapsed weights via uniform s_loads (no LDS, no reduction) ----
    float ew[19];
    #pragma unroll
    for (int t = 0; t < 19; ++t) ew[t] = ws[t];

    // ---- zero arena (conv borders must be 0) ----
    #pragma unroll
    for (int k = 0; k < 29; ++k) {
        int idx = tid + (k << 7);
        if (idx < SMEMN) smem[idx] = 0.f;
    }
    __syncthreads();

    // ---- stage X into padded LDS ----
    #pragma unroll
    for (int k = 0; k < 4; ++k) {
        int e = tid + (k << 7);
        int ch = e >> 8, rem = e & 255;
        smem[XS + ch * 720 + ((rem >> 4) + 1) * ST + (rem & 15) + 1] = xreg[k];
    }
    __syncthreads();

    // ---- r = conv3x3(X, eff_w) + eff_b for this lane's 2 rows ----
    {
        const float* xb = smem + XS + (rg << 1) * ST + c;
        float xt[2][4][3];
        #pragma unroll
        for (int ch = 0; ch < 2; ++ch)
            #pragma unroll
            for (int dy = 0; dy < 4; ++dy)
                #pragma unroll
                for (int dx = 0; dx < 3; ++dx)
                    xt[ch][dy][dx] = xb[ch * 720 + dy * ST + dx];

        #pragma unroll
        for (int k = 0; k < 2; ++k) {
            float acc = ew[18];
            #pragma unroll
            for (int ch = 0; ch < 2; ++ch)
                #pragma unroll
                for (int ky = 0; ky < 3; ++ky)
                    #pragma unroll
                    for (int kx = 0; kx < 3; ++kx)
                        acc += xt[ch][k + ky][kx] * ew[ch * 9 + ky * 3 + kx];
            smem[RP + ((rg << 1) + k + 1) * ST + c + 1] = acc;
        }
    }
    __syncthreads();

    // ---- qr[k][a] = conv3x3(r, q_w)[a] (iteration-invariant half) ----
    float rt[4][3];
    {
        const float* rb = smem + RP + (rg << 1) * ST + c;
        #pragma unroll
        for (int dy = 0; dy < 4; ++dy)
            #pragma unroll
            for (int dx = 0; dx < 3; ++dx)
                rt[dy][dx] = rb[dy * ST + dx];
    }

    float qr[2][LQ];
    #pragma unroll
    for (int a = 0; a < LQ; ++a)
        #pragma unroll
        for (int k = 0; k < 2; ++k) {
            float acc = 0.f;
            #pragma unroll
            for (int ky = 0; ky < 3; ++ky)
                #pragma unroll
                for (int kx = 0; kx < 3; ++kx)
                    acc += rt[k + ky][kx] * qw[a * 9 + ky * 3 + kx];
            qr[k][a] = acc;
        }

    // ---- VI weights + fc via wave-uniform loads -> SGPRs ----
    float wr[LQ * 9];
    #pragma unroll
    for (int t = 0; t < LQ * 9; ++t) wr[t] = w[t];
    float fc[LQ];
    #pragma unroll
    for (int a = 0; a < LQ; ++a) fc[a] = fcw[a];

    // ---- v0 = max_a qr ----
    #pragma unroll
    for (int k = 0; k < 2; ++k) {
        float m = qr[k][0];
        #pragma unroll
        for (int a = 1; a < LQ; ++a) m = fmaxf(m, qr[k][a]);
        smem[VP + ((rg << 1) + k + 1) * ST + c + 1] = m;
    }
    __syncthreads();

    // ---- 19 VI sweeps: pointer base + imm offsets, 1 barrier/step ----
#define VSTEP(SRC, DST)                                                        \
    {                                                                          \
        const float* vb = smem + VP + (SRC) + (rg << 1) * ST + c;              \
        float vt[4][3];                                                        \
        _Pragma("unroll")                                                      \
        for (int dy = 0; dy < 4; ++dy)                                         \
            _Pragma("unroll")                                                  \
            for (int dx = 0; dx < 3; ++dx)                                     \
                vt[dy][dx] = vb[dy * ST + dx];                                 \
        float m0, m1;                                                          \
        _Pragma("unroll")                                                      \
        for (int a = 0; a < LQ; ++a) {                                         \
            float a0 = qr[0][a], a1 = qr[1][a];                                \
            _Pragma("unroll")                                                  \
            for (int dy = 0; dy < 3; ++dy) {                                   \
                const float w0 = wr[a * 9 + dy * 3 + 0];                       \
                const float w1 = wr[a * 9 + dy * 3 + 1];                       \
                const float w2 = wr[a * 9 + dy * 3 + 2];                       \
                a0 += vt[0 + dy][0] * w0; a0 += vt[0 + dy][1] * w1;            \
                a0 += vt[0 + dy][2] * w2;                                      \
                a1 += vt[1 + dy][0] * w0; a1 += vt[1 + dy][1] * w1;            \
                a1 += vt[1 + dy][2] * w2;                                      \
            }                                                                  \
            if (a == 0) { m0 = a0; m1 = a1; }                                  \
            else        { m0 = fmaxf(m0, a0); m1 = fmaxf(m1, a1); }            \
        }                                                                      \
        float* wb = smem + VP + (DST) + ((rg << 1) + 1) * ST + c + 1;          \
        wb[0]  = m0;                                                           \
        wb[ST] = m1;                                                           \
        __syncthreads();                                                       \
    }

    #pragma unroll 1
    for (int it = 0; it < 9; ++it) {
        VSTEP(0, VB)
        VSTEP(VB, 0)
    }
    VSTEP(0, VB)   // step 19; final v in VP+VB

    // ---- final conv + gather + fc at (s1, s2) only ----
    const float s1f = S1[b], s2f = S2[b];
    int s1 = (int)floorf((s1f + 50.0f) / 6.25f);
    int s2 = (int)floorf((s2f + 50.0f) / 6.25f);
    s1 = min(max(s1, 0), 15);
    s2 = min(max(s2, 0), 15);

    if (rg == (s1 >> 1) && c == s2) {
        float d0 = 0.f, d1 = 0.f;
        #pragma unroll
        for (int a = 0; a < LQ; ++a) {
            d0 += fc[a] * qr[0][a];
            d1 += fc[a] * qr[1][a];
        }
        float logit = ((s1 & 1) == 0) ? d0 : d1;
        #pragma unroll
        for (int ky = 0; ky < 3; ++ky)
            #pragma unroll
            for (int kx = 0; kx < 3; ++kx)
                logit += smem[VP + VB + (s1 + ky) * ST + s2 + kx]
                       * ws[19 + ky * 3 + kx];
        out[b]       = logit;   // logits
        out[B_N + b] = 1.0f;    // softmax over length-1 axis == 1
    }
#undef VSTEP
}

extern "C" void kernel_launch(void* const* d_in, const int* in_sizes, int n_in,
                              void* d_out, int out_size, void* d_ws, size_t ws_size,
                              hipStream_t stream) {
    const float* X    = (const float*)d_in[0];
    const float* S1   = (const float*)d_in[1];
    const float* S2   = (const float*)d_in[2];
    const float* h_w  = (const float*)d_in[3];
    const float* h_b  = (const float*)d_in[4];
    const float* r_w  = (const float*)d_in[5];
    const float* q_w  = (const float*)d_in[6];
    const float* w    = (const float*)d_in[7];
    const float* fc_w = (const float*)d_in[8];
    float*       out  = (float*)d_out;
    float*       ws   = (float*)d_ws;

    vin_precompute<<<1, 64, 0, stream>>>(h_w, h_b, r_w, w, fc_w, ws);
    vin_kernel<<<B_N, 128, 0, stream>>>(X, S1, S2, q_w, w, fc_w, ws, out);
}

// Round 11
// 45.008 us; speedup vs baseline: 1.4260x; 1.0159x over previous
//
#include <hip/hip_runtime.h>

#define B_N   2048
#define LQ    10
#define LH    150

// ---------------- pre-kernel: collapse the linear layers once ----------------
// ws layout (floats): [0..17] eff_w (ch*9+ky*3+kx), [18] eff_b, [19..27] fw
__global__ void vin_precompute(const float* __restrict__ h_w,
                               const float* __restrict__ h_b,
                               const float* __restrict__ r_w,
                               const float* __restrict__ w,
                               const float* __restrict__ fc_w,
                               float* __restrict__ ws) {
    const int t = threadIdx.x;
    if (t < 18) {
        float acc = 0.f;
        #pragma unroll 3
        for (int h = 0; h < LH; ++h) acc += r_w[h] * h_w[h * 18 + t];
        ws[t] = acc;
    } else if (t == 18) {
        float acc = 0.f;
        #pragma unroll 3
        for (int h = 0; h < LH; ++h) acc += r_w[h] * h_b[h];
        ws[18] = acc;
    } else if (t < 28) {
        const int tt = t - 19;
        float acc = 0.f;
        #pragma unroll
        for (int a = 0; a < LQ; ++a) acc += fc_w[a] * w[a * 9 + tt];
        ws[19 + tt] = acc;
    }
}

// ---------------- main kernel ----------------
// 256 threads = 2 BATCH ELEMENTS per block (1024 blocks). Each half-block is
// exactly R10's proven 2-wave structure. Rationale: R8/R9/R10 counters show
// ~4 blocks resident/CU regardless of block size, so 128-thr blocks strand
// half the wave slots (Occupancy 25%); 256-thr blocks reached 60% (R9). R9's
// regression came from __launch_bounds__(256,8)'s VGPR-32 cap, not the block
// size -- here we use (256,4) (cap 128) to keep R10's codegen (VGPR 40,
// weights in SGPRs).
//
// Per-half LDS arena (2160 floats, ROW STRIDE 40 -> 2-way bank aliasing, free):
//   XS base+[0,1440)    : padded X, ch*720 + (row+1)*40 + (col+1)
//   RP base+[1440,2160) : padded r
//   VP base+[0,1440)    : double-buffered padded v -- ALIASES XS (X is dead
//                         after the r-conv; staging/v0 only write interior
//                         cells, so the zeroed borders survive).
#define ST    40
#define RPOF  1440
#define VB    720
#define HALFN 2160

__global__ __launch_bounds__(256, 4) void vin_kernel(
    const float* __restrict__ X,   const float* __restrict__ S1,
    const float* __restrict__ S2,  const float* __restrict__ qw,
    const float* __restrict__ w,   const float* __restrict__ fcw,
    const float* __restrict__ ws,  float* __restrict__ out)
{
    __shared__ float smem[2 * HALFN];

    const int tid  = threadIdx.x;
    const int half = tid >> 7;           // which batch element of the pair
    const int t    = tid & 127;
    const int rg   = t >> 4;             // 0..7: owns rows 2rg, 2rg+1
    const int c    = t & 15;
    const int b    = 2 * blockIdx.x + half;

    float* base = smem + half * HALFN;

    // ---- issue X loads first ----
    const float* Xb = X + (size_t)b * 512;
    float xreg[4];
    #pragma unroll
    for (int k = 0; k < 4; ++k) xreg[k] = Xb[t + (k << 7)];

    // ---- collapsed weights via uniform s_loads ----
    float ew[19];
    #pragma unroll
    for (int tt = 0; tt < 19; ++tt) ew[tt] = ws[tt];

    // ---- zero both arenas (conv borders must be 0) ----
    #pragma unroll
    for (int k = 0; k < 17; ++k) {
        int idx = tid + (k << 8);
        if (idx < 2 * HALFN) smem[idx] = 0.f;
    }
    __syncthreads();

    // ---- stage X into padded LDS (interior cells only) ----
    #pragma unroll
    for (int k = 0; k < 4; ++k) {
        int e = t + (k << 7);
        int ch = e >> 8, rem = e & 255;
        base[ch * 720 + ((rem >> 4) + 1) * ST + (rem & 15) + 1] = xreg[k];
    }
    __syncthreads();

    // ---- r = conv3x3(X, eff_w) + eff_b for this lane's 2 rows ----
    {
        const float* xb = base + (rg << 1) * ST + c;
        float xt[2][4][3];
        #pragma unroll
        for (int ch = 0; ch < 2; ++ch)
            #pragma unroll
            for (int dy = 0; dy < 4; ++dy)
                #pragma unroll
                for (int dx = 0; dx < 3; ++dx)
                    xt[ch][dy][dx] = xb[ch * 720 + dy * ST + dx];

        #pragma unroll
        for (int k = 0; k < 2; ++k) {
            float acc = ew[18];
            #pragma unroll
            for (int ch = 0; ch < 2; ++ch)
                #pragma unroll
                for (int ky = 0; ky < 3; ++ky)
                    #pragma unroll
                    for (int kx = 0; kx < 3; ++kx)
                        acc += xt[ch][k + ky][kx] * ew[ch * 9 + ky * 3 + kx];
            base[RPOF + ((rg << 1) + k + 1) * ST + c + 1] = acc;
        }
    }
    __syncthreads();

    // ---- qr[k][a] = conv3x3(r, q_w)[a] (iteration-invariant half) ----
    float rt[4][3];
    {
        const float* rb = base + RPOF + (rg << 1) * ST + c;
        #pragma unroll
        for (int dy = 0; dy < 4; ++dy)
            #pragma unroll
            for (int dx = 0; dx < 3; ++dx)
                rt[dy][dx] = rb[dy * ST + dx];
    }

    float qr[2][LQ];
    #pragma unroll
    for (int a = 0; a < LQ; ++a)
        #pragma unroll
        for (int k = 0; k < 2; ++k) {
            float acc = 0.f;
            #pragma unroll
            for (int ky = 0; ky < 3; ++ky)
                #pragma unroll
                for (int kx = 0; kx < 3; ++kx)
                    acc += rt[k + ky][kx] * qw[a * 9 + ky * 3 + kx];
            qr[k][a] = acc;
        }

    // ---- VI weights + fc via wave-uniform loads -> SGPRs ----
    float wr[LQ * 9];
    #pragma unroll
    for (int tt = 0; tt < LQ * 9; ++tt) wr[tt] = w[tt];
    float fc[LQ];
    #pragma unroll
    for (int a = 0; a < LQ; ++a) fc[a] = fcw[a];

    // ---- v0 = max_a qr -> VP interior (overwrites dead X ch0 interior) ----
    #pragma unroll
    for (int k = 0; k < 2; ++k) {
        float m = qr[k][0];
        #pragma unroll
        for (int a = 1; a < LQ; ++a) m = fmaxf(m, qr[k][a]);
        base[((rg << 1) + k + 1) * ST + c + 1] = m;
    }
    __syncthreads();

    // ---- 19 VI sweeps: 1 barrier/step ----
#define VSTEP(SRC, DST)                                                        \
    {                                                                          \
        const float* vb = base + (SRC) + (rg << 1) * ST + c;                   \
        float vt[4][3];                                                        \
        _Pragma("unroll")                                                      \
        for (int dy = 0; dy < 4; ++dy)                                         \
            _Pragma("unroll")                                                  \
            for (int dx = 0; dx < 3; ++dx)                                     \
                vt[dy][dx] = vb[dy * ST + dx];                                 \
        float m0, m1;                                                          \
        _Pragma("unroll")                                                      \
        for (int a = 0; a < LQ; ++a) {                                         \
            float a0 = qr[0][a], a1 = qr[1][a];                                \
            _Pragma("unroll")                                                  \
            for (int dy = 0; dy < 3; ++dy) {                                   \
                const float w0 = wr[a * 9 + dy * 3 + 0];                       \
                const float w1 = wr[a * 9 + dy * 3 + 1];                       \
                const float w2 = wr[a * 9 + dy * 3 + 2];                       \
                a0 += vt[0 + dy][0] * w0; a0 += vt[0 + dy][1] * w1;            \
                a0 += vt[0 + dy][2] * w2;                                      \
                a1 += vt[1 + dy][0] * w0; a1 += vt[1 + dy][1] * w1;            \
                a1 += vt[1 + dy][2] * w2;                                      \
            }                                                                  \
            if (a == 0) { m0 = a0; m1 = a1; }                                  \
            else        { m0 = fmaxf(m0, a0); m1 = fmaxf(m1, a1); }            \
        }                                                                      \
        float* wb = base + (DST) + ((rg << 1) + 1) * ST + c + 1;               \
        wb[0]  = m0;                                                           \
        wb[ST] = m1;                                                           \
        __syncthreads();                                                       \
    }

    #pragma unroll 1
    for (int it = 0; it < 9; ++it) {
        VSTEP(0, VB)
        VSTEP(VB, 0)
    }
    VSTEP(0, VB)   // step 19; final v in base+VB

    // ---- final conv + gather + fc at (s1, s2) only ----
    const float s1f = S1[b], s2f = S2[b];
    int s1 = (int)floorf((s1f + 50.0f) / 6.25f);
    int s2 = (int)floorf((s2f + 50.0f) / 6.25f);
    s1 = min(max(s1, 0), 15);
    s2 = min(max(s2, 0), 15);

    if (rg == (s1 >> 1) && c == s2) {
        float d0 = 0.f, d1 = 0.f;
        #pragma unroll
        for (int a = 0; a < LQ; ++a) {
            d0 += fc[a] * qr[0][a];
            d1 += fc[a] * qr[1][a];
        }
        float logit = ((s1 & 1) == 0) ? d0 : d1;
        #pragma unroll
        for (int ky = 0; ky < 3; ++ky)
            #pragma unroll
            for (int kx = 0; kx < 3; ++kx)
                logit += base[VB + (s1 + ky) * ST + s2 + kx]
                       * ws[19 + ky * 3 + kx];
        out[b]       = logit;   // logits
        out[B_N + b] = 1.0f;    // softmax over length-1 axis == 1
    }
#undef VSTEP
}

extern "C" void kernel_launch(void* const* d_in, const int* in_sizes, int n_in,
                              void* d_out, int out_size, void* d_ws, size_t ws_size,
                              hipStream_t stream) {
    const float* X    = (const float*)d_in[0];
    const float* S1   = (const float*)d_in[1];
    const float* S2   = (const float*)d_in[2];
    const float* h_w  = (const float*)d_in[3];
    const float* h_b  = (const float*)d_in[4];
    const float* r_w  = (const float*)d_in[5];
    const float* q_w  = (const float*)d_in[6];
    const float* w    = (const float*)d_in[7];
    const float* fc_w = (const float*)d_in[8];
    float*       out  = (float*)d_out;
    float*       ws   = (float*)d_ws;

    vin_precompute<<<1, 64, 0, stream>>>(h_w, h_b, r_w, w, fc_w, ws);
    vin_kernel<<<B_N / 2, 256, 0, stream>>>(X, S1, S2, q_w, w, fc_w, ws, out);
}

// Round 12
// 31.307 us; speedup vs baseline: 2.0500x; 1.4376x over previous
//
#include <hip/hip_runtime.h>

#define B_N   2048
#define LQ    10
#define LH    150

typedef float pf2 __attribute__((ext_vector_type(2)));

// ws float layout:
//   [0..17]   eff_w (ch*9+ky*3+kx)     [18] eff_b      [19..27] fw
//   [30..119] qwpk: float2[45]  {q_w[2ap][t], q_w[2ap+1][t]}, idx=ap*9+t
//   [120..209] wpk: float2[45]  {w[2ap][t],  w[2ap+1][t]},   idx=ap*9+t
#define QWPK 30
#define WPK  120

// ---------------- pre-kernel: wide (1 block x 256 thr), ~1us ----------------
__global__ __launch_bounds__(256) void vin_precompute(
    const float* __restrict__ h_w, const float* __restrict__ h_b,
    const float* __restrict__ r_w, const float* __restrict__ q_w,
    const float* __restrict__ w,   const float* __restrict__ fc_w,
    float* __restrict__ ws)
{
    const int lane = threadIdx.x;
    if (lane < 152) {
        // 19 outputs x 8 lanes: t<18 -> eff_w[t], t==18 -> eff_b
        const int t = lane >> 3, j = lane & 7;
        float part = 0.f;
        if (t < 18) { for (int h = j; h < LH; h += 8) part += r_w[h] * h_w[h * 18 + t]; }
        else        { for (int h = j; h < LH; h += 8) part += r_w[h] * h_b[h]; }
        part += __shfl_down(part, 4, 8);
        part += __shfl_down(part, 2, 8);
        part += __shfl_down(part, 1, 8);
        if (j == 0) ws[t] = part;
    } else if (lane >= 152 && lane < 161) {
        const int t = lane - 152;
        float acc = 0.f;
        #pragma unroll
        for (int a = 0; a < LQ; ++a) acc += fc_w[a] * w[a * 9 + t];
        ws[19 + t] = acc;
    } else if (lane >= 161 && lane < 206) {
        const int idx = lane - 161, ap = idx / 9, t = idx - ap * 9;
        ws[QWPK + 2 * idx]     = q_w[(2 * ap)     * 9 + t];
        ws[QWPK + 2 * idx + 1] = q_w[(2 * ap + 1) * 9 + t];
    } else if (lane >= 206 && lane < 251) {
        const int idx = lane - 206, ap = idx / 9, t = idx - ap * 9;
        ws[WPK + 2 * idx]     = w[(2 * ap)     * 9 + t];
        ws[WPK + 2 * idx + 1] = w[(2 * ap + 1) * 9 + t];
    }
}

// ---------------- main kernel ----------------
// 256 threads = 2 batch elements/block (1024 blocks), R11 structure.
// Per-half LDS arena (2160 floats, ROW STRIDE 40 -> 2-way bank alias, free):
//   XS base+[0,1440)    : padded X, ch*720 + (row+1)*40 + (col+1)
//   RP base+[1440,2160) : padded r
//   VP base+[0,1440)    : double-buffered padded v (ALIASES dead X; borders
//                         stay zero -- interior-only writes)
// VI inner loop: ACTION-PAIR packed fp32 (v_pk_fma_f32): acc2={q[2a],q[2a+1]},
// weight operand = wave-uniform float2 (SGPR pair, the single legal SGPR src),
// tap = VGPR splat (op_sel_hi broadcast, no materialization). Halves VALU
// issue of the 90-FMA burst. No runtime indexing into register arrays.
#define ST    40
#define RPOF  1440
#define VB    720
#define HALFN 2160

__global__ __launch_bounds__(256, 4) void vin_kernel(
    const float* __restrict__ X,   const float* __restrict__ S1,
    const float* __restrict__ S2,  const float* __restrict__ fcw,
    const float* __restrict__ ws,  float* __restrict__ out)
{
    __shared__ float smem[2 * HALFN];

    const int tid  = threadIdx.x;
    const int half = tid >> 7;
    const int t    = tid & 127;
    const int rg   = t >> 4;             // 0..7: owns rows 2rg, 2rg+1
    const int c    = t & 15;
    const int b    = 2 * blockIdx.x + half;

    float* base = smem + half * HALFN;

    // ---- issue X loads first ----
    const float* Xb = X + (size_t)b * 512;
    float xreg[4];
    #pragma unroll
    for (int k = 0; k < 4; ++k) xreg[k] = Xb[t + (k << 7)];

    // ---- collapsed weights via uniform s_loads ----
    float ew[19];
    #pragma unroll
    for (int tt = 0; tt < 19; ++tt) ew[tt] = ws[tt];

    // ---- zero both arenas ----
    #pragma unroll
    for (int k = 0; k < 17; ++k) {
        int idx = tid + (k << 8);
        if (idx < 2 * HALFN) smem[idx] = 0.f;
    }
    __syncthreads();

    // ---- stage X (interior cells only) ----
    #pragma unroll
    for (int k = 0; k < 4; ++k) {
        int e = t + (k << 7);
        int ch = e >> 8, rem = e & 255;
        base[ch * 720 + ((rem >> 4) + 1) * ST + (rem & 15) + 1] = xreg[k];
    }
    __syncthreads();

    // ---- r = conv3x3(X, eff_w) + eff_b for this lane's 2 rows ----
    {
        const float* xb = base + (rg << 1) * ST + c;
        float xt[2][4][3];
        #pragma unroll
        for (int ch = 0; ch < 2; ++ch)
            #pragma unroll
            for (int dy = 0; dy < 4; ++dy)
                #pragma unroll
                for (int dx = 0; dx < 3; ++dx)
                    xt[ch][dy][dx] = xb[ch * 720 + dy * ST + dx];

        #pragma unroll
        for (int k = 0; k < 2; ++k) {
            float acc = ew[18];
            #pragma unroll
            for (int ch = 0; ch < 2; ++ch)
                #pragma unroll
                for (int ky = 0; ky < 3; ++ky)
                    #pragma unroll
                    for (int kx = 0; kx < 3; ++kx)
                        acc += xt[ch][k + ky][kx] * ew[ch * 9 + ky * 3 + kx];
            base[RPOF + ((rg << 1) + k + 1) * ST + c + 1] = acc;
        }
    }
    __syncthreads();

    // ---- packed weight tables (wave-uniform -> SGPR pairs) ----
    const pf2* qwp = (const pf2*)(ws + QWPK);
    const pf2* wpk = (const pf2*)(ws + WPK);

    // ---- qr2[k][ap] = packed conv3x3(r, q_w) for action pair ap ----
    float rt[4][3];
    {
        const float* rb = base + RPOF + (rg << 1) * ST + c;
        #pragma unroll
        for (int dy = 0; dy < 4; ++dy)
            #pragma unroll
            for (int dx = 0; dx < 3; ++dx)
                rt[dy][dx] = rb[dy * ST + dx];
    }

    pf2 qr2[2][5];
    #pragma unroll
    for (int k = 0; k < 2; ++k)
        #pragma unroll
        for (int ap = 0; ap < 5; ++ap) {
            pf2 acc = {0.f, 0.f};
            #pragma unroll
            for (int tt = 0; tt < 9; ++tt) {
                const float tap = rt[k + tt / 3][tt % 3];
                pf2 ts = {tap, tap};
                acc = __builtin_elementwise_fma(ts, qwp[ap * 9 + tt], acc);
            }
            qr2[k][ap] = acc;
        }

    float fc[LQ];
    #pragma unroll
    for (int a = 0; a < LQ; ++a) fc[a] = fcw[a];

    // ---- v0 = max over 10 actions ----
    #pragma unroll
    for (int k = 0; k < 2; ++k) {
        float m = fmaxf(qr2[k][0].x, qr2[k][0].y);
        #pragma unroll
        for (int ap = 1; ap < 5; ++ap)
            m = fmaxf(m, fmaxf(qr2[k][ap].x, qr2[k][ap].y));
        base[((rg << 1) + k + 1) * ST + c + 1] = m;
    }
    __syncthreads();

    // ---- 19 VI sweeps: packed-fp32 inner loop, 1 barrier/step ----
#define VSTEP(SRC, DST)                                                        \
    {                                                                          \
        const float* vb = base + (SRC) + (rg << 1) * ST + c;                   \
        float vt[4][3];                                                        \
        _Pragma("unroll")                                                      \
        for (int dy = 0; dy < 4; ++dy)                                         \
            _Pragma("unroll")                                                  \
            for (int dx = 0; dx < 3; ++dx)                                     \
                vt[dy][dx] = vb[dy * ST + dx];                                 \
        float m0, m1;                                                          \
        {                                                                      \
            pf2 a0_[5], a1_[5];                                                \
            _Pragma("unroll")                                                  \
            for (int ap = 0; ap < 5; ++ap) { a0_[ap] = qr2[0][ap]; a1_[ap] = qr2[1][ap]; } \
            _Pragma("unroll")                                                  \
            for (int tt = 0; tt < 9; ++tt) {                                   \
                const int dy = tt / 3, dx = tt % 3;                            \
                const float tap0 = vt[dy][dx];                                 \
                const float tap1 = vt[dy + 1][dx];                             \
                pf2 t0 = {tap0, tap0};                                         \
                pf2 t1 = {tap1, tap1};                                         \
                _Pragma("unroll")                                              \
                for (int ap = 0; ap < 5; ++ap) {                               \
                    const pf2 wv = wpk[ap * 9 + tt];                           \
                    a0_[ap] = __builtin_elementwise_fma(t0, wv, a0_[ap]);      \
                    a1_[ap] = __builtin_elementwise_fma(t1, wv, a1_[ap]);      \
                }                                                              \
            }                                                                  \
            m0 = fmaxf(a0_[0].x, a0_[0].y);                                    \
            m1 = fmaxf(a1_[0].x, a1_[0].y);                                    \
            _Pragma("unroll")                                                  \
            for (int ap = 1; ap < 5; ++ap) {                                   \
                m0 = fmaxf(m0, fmaxf(a0_[ap].x, a0_[ap].y));                   \
                m1 = fmaxf(m1, fmaxf(a1_[ap].x, a1_[ap].y));                   \
            }                                                                  \
        }                                                                      \
        float* wb = base + (DST) + ((rg << 1) + 1) * ST + c + 1;               \
        wb[0]  = m0;                                                           \
        wb[ST] = m1;                                                           \
        __syncthreads();                                                       \
    }

    #pragma unroll 1
    for (int it = 0; it < 9; ++it) {
        VSTEP(0, VB)
        VSTEP(VB, 0)
    }
    VSTEP(0, VB)   // step 19; final v in base+VB

    // ---- final conv + gather + fc at (s1, s2) only ----
    const float s1f = S1[b], s2f = S2[b];
    int s1 = (int)floorf((s1f + 50.0f) / 6.25f);
    int s2 = (int)floorf((s2f + 50.0f) / 6.25f);
    s1 = min(max(s1, 0), 15);
    s2 = min(max(s2, 0), 15);

    if (rg == (s1 >> 1) && c == s2) {
        float d0 = 0.f, d1 = 0.f;
        #pragma unroll
        for (int ap = 0; ap < 5; ++ap) {
            d0 += fc[2 * ap] * qr2[0][ap].x + fc[2 * ap + 1] * qr2[0][ap].y;
            d1 += fc[2 * ap] * qr2[1][ap].x + fc[2 * ap + 1] * qr2[1][ap].y;
        }
        float logit = ((s1 & 1) == 0) ? d0 : d1;
        #pragma unroll
        for (int ky = 0; ky < 3; ++ky)
            #pragma unroll
            for (int kx = 0; kx < 3; ++kx)
                logit += base[VB + (s1 + ky) * ST + s2 + kx]
                       * ws[19 + ky * 3 + kx];
        out[b]       = logit;   // logits
        out[B_N + b] = 1.0f;    // softmax over length-1 axis == 1
    }
#undef VSTEP
}

extern "C" void kernel_launch(void* const* d_in, const int* in_sizes, int n_in,
                              void* d_out, int out_size, void* d_ws, size_t ws_size,
                              hipStream_t stream) {
    const float* X    = (const float*)d_in[0];
    const float* S1   = (const float*)d_in[1];
    const float* S2   = (const float*)d_in[2];
    const float* h_w  = (const float*)d_in[3];
    const float* h_b  = (const float*)d_in[4];
    const float* r_w  = (const float*)d_in[5];
    const float* q_w  = (const float*)d_in[6];
    const float* w    = (const float*)d_in[7];
    const float* fc_w = (const float*)d_in[8];
    float*       out  = (float*)d_out;
    float*       ws   = (float*)d_ws;

    vin_precompute<<<1, 256, 0, stream>>>(h_w, h_b, r_w, q_w, w, fc_w, ws);
    vin_kernel<<<B_N / 2, 256, 0, stream>>>(X, S1, S2, fc_w, ws, out);
}